// Round 6
// baseline (234.752 us; speedup 1.0000x reference)
//
#include <hip/hip_runtime.h>
#include <hip/hip_bf16.h>

#define BB   128
#define CIN  9
#define TT   2048
#define RR   512
#define NN   (BB*RR)     // 65536
#define HID  128
#define NOUT 12

typedef __attribute__((ext_vector_type(8))) short short8;
typedef __attribute__((ext_vector_type(4))) float f32x4;

static __device__ inline unsigned short f2bf(float f) {       // RNE f32->bf16
    unsigned int u = __float_as_uint(f);
    unsigned int r = (u + 0x7fffu + ((u >> 16) & 1u)) >> 16;
    return (unsigned short)r;
}
static __device__ inline float bf2f(unsigned short u) {
    return __uint_as_float(((unsigned int)u) << 16);
}

// =======================================================================
// k_convs: [unchanged from R4/R5 — conv taps via wave-uniform s_load]
//   block 0       : tiny prep — zero meanbuf/done, W2^T bf16 transpose.
//   blocks 1..64  : dense-A build, 8 rows each, LDS-local.
//   blocks 65..1088: fused conv1+relu+pool2 -> conv2+relu+pool2 -> nodesT.
// =======================================================================
__global__ __launch_bounds__(512) void k_convs(const float* __restrict__ x,
        const float* __restrict__ w1, const float* __restrict__ b1,
        const float* __restrict__ w2, const float* __restrict__ b2,
        unsigned short* __restrict__ nodesT,
        const int* __restrict__ ei, int E, int es,
        unsigned short* __restrict__ Ab16,
        const float* __restrict__ g2w, unsigned short* __restrict__ w2t,
        float* __restrict__ meanbuf, int* __restrict__ done) {
    __shared__ __align__(16) union {
        struct { float sx[CIN][268]; float s1[16][132]; } c;   // conv: 18.1 KB
        struct { int cnt[512]; float arow[8][512]; } a;        // A-build: 18.4 KB
    } u;
    int tid = threadIdx.x;
    int bid = blockIdx.x;

    if (bid == 0) {                    // ---- tiny prep ----
        float4 z = make_float4(0.f, 0.f, 0.f, 0.f);
        for (int i = tid; i < 128 * 128 / 4; i += 512) ((float4*)meanbuf)[i] = z;
        if (tid < 128) done[tid] = 0;
        for (int idx = tid; idx < 128 * 128; idx += 512) {
            int c2 = idx >> 7, f = idx & 127;
            w2t[f * 128 + c2] = f2bf(g2w[idx]);
        }
        return;
    }

    if (bid <= 64) {                   // ---- dense-A build: rows [base, base+8) ----
        int base = (bid - 1) * 8;
        u.a.cnt[tid] = 0;
        float4 z = make_float4(0.f, 0.f, 0.f, 0.f);
        float4* az = (float4*)u.a.arow;      // 1024 float4
        az[tid] = z; az[tid + 512] = z;
        __syncthreads();
        for (int i = tid; i < es; i += 512) atomicAdd(&u.a.cnt[ei[E + i]], 1);
        __syncthreads();
        for (int i = tid; i < es; i += 512) {
            int c = ei[E + i];
            if (c >= base && c < base + 8) {
                int r = ei[i];
                float nd = rsqrtf((float)u.a.cnt[r] + 1.0f);
                float dn = rsqrtf((float)u.a.cnt[c] + 1.0f);
                atomicAdd(&u.a.arow[c - base][r], nd * dn);
            }
        }
        if (tid < 8) {                 // self loop
            int r = base + tid;
            float d = rsqrtf((float)u.a.cnt[r] + 1.0f);
            atomicAdd(&u.a.arow[tid][r], d * d);
        }
        __syncthreads();
        {   // convert 8x512 fp32 -> bf16, coalesced row stores
            int row = tid >> 6, c0 = (tid & 63) * 8;
            const float* p = &u.a.arow[row][c0];
            ushort4 o0, o1;
            o0.x = f2bf(p[0]); o0.y = f2bf(p[1]); o0.z = f2bf(p[2]); o0.w = f2bf(p[3]);
            o1.x = f2bf(p[4]); o1.y = f2bf(p[5]); o1.z = f2bf(p[6]); o1.w = f2bf(p[7]);
            *(ushort4*)&Ab16[(size_t)(base + row) * 512 + c0]     = o0;
            *(ushort4*)&Ab16[(size_t)(base + row) * 512 + c0 + 4] = o1;
        }
        return;
    }

    int cb = bid - 65;
    int b  = cb >> 3;
    int r0 = (cb & 7) * 64;
    int wv   = __builtin_amdgcn_readfirstlane(tid >> 6);   // wave 0..7
    int lane = tid & 63;

    for (int idx = tid; idx < CIN * 268; idx += 512) {
        int c = idx / 268, j = idx - c * 268;
        int g = 4 * r0 - 6 + j;
        float v = 0.f;
        if (g >= 0 && g < TT) v = x[(b * CIN + c) * TT + g];
        u.c.sx[c][j] = v;
    }
    __syncthreads();

    // phase B: wave wv covers channels wv*2, wv*2+1 (taps via s_load)
    {
        int c1a = wv * 2, c1b = wv * 2 + 1;
        float biasA = b1[c1a], biasB = b1[c1b];
        for (int pp = lane; pp < 132; pp += 64) {
            int p = 2 * r0 - 2 + pp;
            float valA = 0.f, valB = 0.f;
            if (p >= 0 && p < 1024) {
                float a0A = biasA, a1A = biasA, a0B = biasB, a1B = biasB;
#pragma unroll
                for (int c = 0; c < CIN; ++c) {
                    const float2* px = (const float2*)&u.c.sx[c][2 * pp];
                    float2 q0 = px[0], q1 = px[1], q2 = px[2];
                    {
                        const float* wp = &w1[(c1a * CIN + c) * 5];
                        float k0 = wp[0], k1 = wp[1], k2 = wp[2], k3 = wp[3], k4 = wp[4];
                        a0A += q0.x*k0 + q0.y*k1 + q1.x*k2 + q1.y*k3 + q2.x*k4;
                        a1A += q0.y*k0 + q1.x*k1 + q1.y*k2 + q2.x*k3 + q2.y*k4;
                    }
                    {
                        const float* wp = &w1[(c1b * CIN + c) * 5];
                        float k0 = wp[0], k1 = wp[1], k2 = wp[2], k3 = wp[3], k4 = wp[4];
                        a0B += q0.x*k0 + q0.y*k1 + q1.x*k2 + q1.y*k3 + q2.x*k4;
                        a1B += q0.y*k0 + q1.x*k1 + q1.y*k2 + q2.x*k3 + q2.y*k4;
                    }
                }
                valA = fmaxf(fmaxf(a0A, a1A), 0.f);
                valB = fmaxf(fmaxf(a0B, a1B), 0.f);
            }
            u.c.s1[c1a][pp] = valA;
            u.c.s1[c1b][pp] = valB;
        }
    }
    __syncthreads();

    // phase C: wave wv covers channels wv*4..wv*4+3 -> nodesT bf16
    int rl = lane;
    float acc0[4], acc1[4];
#pragma unroll
    for (int o = 0; o < 4; ++o) {
        float bv = b2[wv * 4 + o];
        acc0[o] = bv; acc1[o] = bv;
    }
#pragma unroll
    for (int c = 0; c < 16; ++c) {
        const float2* ps = (const float2*)&u.c.s1[c][2 * rl];
        float2 q0 = ps[0], q1 = ps[1], q2 = ps[2];
#pragma unroll
        for (int o = 0; o < 4; ++o) {
            const float* wp = &w2[((wv * 4 + o) * 16 + c) * 5];
            float k0 = wp[0], k1 = wp[1], k2 = wp[2], k3 = wp[3], k4 = wp[4];
            acc0[o] += q0.x*k0 + q0.y*k1 + q1.x*k2 + q1.y*k3 + q2.x*k4;
            acc1[o] += q0.y*k0 + q1.x*k1 + q1.y*k2 + q2.x*k3 + q2.y*k4;
        }
    }
    int n = r0 + rl;
    unsigned short* np = nodesT + ((size_t)b * 32 + wv * 4) * 512 + n;
    np[0]    = f2bf(fmaxf(fmaxf(acc0[0], acc1[0]), 0.f));
    np[512]  = f2bf(fmaxf(fmaxf(acc0[1], acc1[1]), 0.f));
    np[1024] = f2bf(fmaxf(fmaxf(acc0[2], acc1[2]), 0.f));
    np[1536] = f2bf(fmaxf(fmaxf(acc0[3], acc1[3]), 0.f));
}

// =======================================================================
// k_agg1: [unchanged from R4]
// =======================================================================
__global__ __launch_bounds__(256) void k_agg1(const unsigned short* __restrict__ Ab,
        const unsigned short* __restrict__ nT, const float* __restrict__ w1,
        const float* __restrict__ b1, unsigned short* __restrict__ h16) {
    __shared__ unsigned short sA[128][72];
    __shared__ unsigned short sN[32][72];
    __shared__ float sAgg[128][33];
    __shared__ float sw1[32 * 128];
    int tid = threadIdx.x;
    int b  = blockIdx.x >> 2;
    int rb = blockIdx.x & 3;
    int r0 = rb * 128;
    const unsigned short* nb = nT + (size_t)b * 32 * 512;

    {
        const float4* src = (const float4*)w1;
        float4* dst = (float4*)sw1;
#pragma unroll
        for (int i = 0; i < 4; ++i) dst[tid + i * 256] = src[tid + i * 256];
    }

    int wv = tid >> 6, lane = tid & 63;
    int l15 = lane & 15, quad = lane >> 4;
    int mB = wv * 32;
    f32x4 acc[2][2];
#pragma unroll
    for (int i = 0; i < 2; ++i)
#pragma unroll
        for (int j = 0; j < 2; ++j) acc[i][j] = (f32x4){0.f, 0.f, 0.f, 0.f};

    for (int kt = 0; kt < 8; ++kt) {
        int k0 = kt * 64;
        __syncthreads();
#pragma unroll
        for (int i = 0; i < 8; ++i) {
            int idx = tid + i * 256;
            int row = idx >> 4, c4 = (idx & 15) * 4;
            *(ushort4*)&sA[row][c4] = *(const ushort4*)&Ab[(size_t)(r0 + row) * 512 + k0 + c4];
        }
#pragma unroll
        for (int i = 0; i < 2; ++i) {
            int idx = tid + i * 256;
            int f = idx >> 4, c4 = (idx & 15) * 4;
            *(ushort4*)&sN[f][c4] = *(const ushort4*)&nb[(size_t)f * 512 + k0 + c4];
        }
        __syncthreads();
#pragma unroll
        for (int ks = 0; ks < 2; ++ks) {
            int kk = ks * 32 + quad * 8;
            short8 av0 = *(const short8*)&sA[mB + l15][kk];
            short8 av1 = *(const short8*)&sA[mB + 16 + l15][kk];
            short8 bv0 = *(const short8*)&sN[l15][kk];
            short8 bv1 = *(const short8*)&sN[16 + l15][kk];
            acc[0][0] = __builtin_amdgcn_mfma_f32_16x16x32_bf16(av0, bv0, acc[0][0], 0, 0, 0);
            acc[0][1] = __builtin_amdgcn_mfma_f32_16x16x32_bf16(av0, bv1, acc[0][1], 0, 0, 0);
            acc[1][0] = __builtin_amdgcn_mfma_f32_16x16x32_bf16(av1, bv0, acc[1][0], 0, 0, 0);
            acc[1][1] = __builtin_amdgcn_mfma_f32_16x16x32_bf16(av1, bv1, acc[1][1], 0, 0, 0);
        }
    }
    __syncthreads();
#pragma unroll
    for (int mi = 0; mi < 2; ++mi)
#pragma unroll
        for (int ni = 0; ni < 2; ++ni)
#pragma unroll
            for (int r = 0; r < 4; ++r)
                sAgg[mB + mi * 16 + quad * 4 + r][ni * 16 + l15] = acc[mi][ni][r];
    __syncthreads();

    int fq = tid & 31;
    int ng = tid >> 5;
    float4 bv = *(const float4*)&b1[fq * 4];
    for (int ch = 0; ch < 4; ++ch) {
        float a[4][4];
#pragma unroll
        for (int j = 0; j < 4; ++j)
#pragma unroll
            for (int q = 0; q < 4; ++q) a[j][q] = 0.f;
#pragma unroll
        for (int c = 0; c < 32; ++c) {
            float4 wvv = *(const float4*)&sw1[c * 128 + fq * 4];
#pragma unroll
            for (int j = 0; j < 4; ++j) {
                float xc = sAgg[ch * 32 + ng * 4 + j][c];
                a[j][0] += xc * wvv.x; a[j][1] += xc * wvv.y;
                a[j][2] += xc * wvv.z; a[j][3] += xc * wvv.w;
            }
        }
#pragma unroll
        for (int j = 0; j < 4; ++j) {
            ushort4 o;
            o.x = f2bf(fmaxf(a[j][0] + bv.x, 0.f));
            o.y = f2bf(fmaxf(a[j][1] + bv.y, 0.f));
            o.z = f2bf(fmaxf(a[j][2] + bv.z, 0.f));
            o.w = f2bf(fmaxf(a[j][3] + bv.w, 0.f));
            *(ushort4*)&h16[(size_t)(b * 512 + r0 + ch * 32 + ng * 4 + j) * 128 + fq * 4] = o;
        }
    }
}

// =======================================================================
// k_fused2 (v2, f-split): 4 blocks/sample, each owns 32 f-columns.
//   Grid 512, 256 threads (4 waves), ~71 KB LDS -> 2 blocks/CU.
//   smp = bid & 127 so a sample's 4 blocks share an XCD (h1_b L2-resident).
//   Phase 1: tT[32f][512n] = W2chunk^T @ h1^T, h1 read straight from L2
//            (no staging, no barriers); W2^T frags in registers.
//   Phase 2: out[512m][32f] = A_hat @ t; A staged reg->LDS (padded strides,
//            <=2-way banks), prefetch overlaps MFMA; bias+relu+colsum.
//   Epilogue: meanbuf atomics -> done counter -> last of 4 blocks runs fc.
// =======================================================================
__global__ __launch_bounds__(256) void k_fused2(
        const unsigned short* __restrict__ h1,    // [N][128] bf16
        const unsigned short* __restrict__ w2t,   // [128 f][128 c] bf16
        const unsigned short* __restrict__ Ab,    // [512][512] bf16
        const float* __restrict__ b2,
        float* __restrict__ meanbuf, int* __restrict__ done,
        const float* __restrict__ fw, const float* __restrict__ fb,
        float* __restrict__ out) {
    __shared__ __align__(16) unsigned short tT[32][520];   // 33.3 KB, row 1040 B
    __shared__ __align__(16) unsigned short sA[256][72];   // 36.9 KB, row 144 B
    __shared__ float sred[4][32];
    __shared__ float smv[HID];
    __shared__ int slast;

    int tid  = threadIdx.x;
    int smp  = blockIdx.x & 127;       // sample
    int fc   = blockIdx.x >> 7;        // f-chunk 0..3
    int f0   = fc * 32;
    int wv   = __builtin_amdgcn_readfirstlane(tid >> 6);   // 0..3
    int lane = tid & 63;
    int l15  = lane & 15, quad = lane >> 4;
    const unsigned short* hb = h1 + (size_t)smp * 512 * 128;

    // prefetch A tile (mc=0, kt=0) into regs — overlaps all of phase 1
    uint4 stg[8];
#pragma unroll
    for (int i = 0; i < 8; ++i) {
        int idx = tid + i * 256;       // 2048 -> 256 rows x 8 uint4
        int row = idx >> 3, c8 = idx & 7;
        stg[i] = *(const uint4*)&Ab[(size_t)row * 512 + c8 * 8];
    }

    // ---------------- phase 1: tT = W2c^T @ h1^T (no barriers) ----------
    short8 w2r[2][4];
#pragma unroll
    for (int ft = 0; ft < 2; ++ft)
#pragma unroll
        for (int ks = 0; ks < 4; ++ks)
            w2r[ft][ks] = *(const short8*)&w2t[(size_t)(f0 + ft * 16 + l15) * 128 + ks * 32 + quad * 8];

    f32x4 acc1[2][8];
#pragma unroll
    for (int ft = 0; ft < 2; ++ft)
#pragma unroll
        for (int nt = 0; nt < 8; ++nt) acc1[ft][nt] = (f32x4){0.f, 0.f, 0.f, 0.f};
#pragma unroll
    for (int nt = 0; nt < 8; ++nt) {
        int n0 = (wv * 8 + nt) * 16;
#pragma unroll
        for (int ks = 0; ks < 4; ++ks) {
            short8 hf = *(const short8*)&hb[(size_t)(n0 + l15) * 128 + ks * 32 + quad * 8];
            acc1[0][nt] = __builtin_amdgcn_mfma_f32_16x16x32_bf16(w2r[0][ks], hf, acc1[0][nt], 0, 0, 0);
            acc1[1][nt] = __builtin_amdgcn_mfma_f32_16x16x32_bf16(w2r[1][ks], hf, acc1[1][nt], 0, 0, 0);
        }
    }
    // write tT[f][node] (col=lane&15 -> node, row=quad*4+r -> f)
#pragma unroll
    for (int ft = 0; ft < 2; ++ft)
#pragma unroll
        for (int nt = 0; nt < 8; ++nt) {
            int node = (wv * 8 + nt) * 16 + l15;
#pragma unroll
            for (int r = 0; r < 4; ++r)
                tT[ft * 16 + quad * 4 + r][node] = f2bf(acc1[ft][nt][r]);
        }
    __syncthreads();

    // ---------------- phase 2: A_hat @ t, colsum fused -------------------
    float bias[2];
#pragma unroll
    for (int ft = 0; ft < 2; ++ft) bias[ft] = b2[f0 + ft * 16 + l15];
    float colsum[2] = {0.f, 0.f};

    for (int mc = 0; mc < 2; ++mc) {
        f32x4 acc[4][2];
#pragma unroll
        for (int mi = 0; mi < 4; ++mi)
#pragma unroll
            for (int ft = 0; ft < 2; ++ft) acc[mi][ft] = (f32x4){0.f, 0.f, 0.f, 0.f};

        for (int kt = 0; kt < 8; ++kt) {
#pragma unroll
            for (int i = 0; i < 8; ++i) {          // stg -> sA
                int idx = tid + i * 256;
                int row = idx >> 3, c8 = idx & 7;
                *(uint4*)&sA[row][c8 * 8] = stg[i];
            }
            __syncthreads();
            if (!(mc == 1 && kt == 7)) {           // prefetch next tile
                int nmc = (kt == 7) ? 1 : mc;
                int nkt = (kt == 7) ? 0 : kt + 1;
#pragma unroll
                for (int i = 0; i < 8; ++i) {
                    int idx = tid + i * 256;
                    int row = idx >> 3, c8 = idx & 7;
                    stg[i] = *(const uint4*)&Ab[(size_t)(nmc * 256 + row) * 512 + nkt * 64 + c8 * 8];
                }
            }
#pragma unroll
            for (int ks = 0; ks < 2; ++ks) {
                int kk = ks * 32 + quad * 8;
                short8 af[4], bf[2];
#pragma unroll
                for (int mi = 0; mi < 4; ++mi)
                    af[mi] = *(const short8*)&sA[wv * 64 + mi * 16 + l15][kk];
#pragma unroll
                for (int ft = 0; ft < 2; ++ft)
                    bf[ft] = *(const short8*)&tT[ft * 16 + l15][kt * 64 + kk];
#pragma unroll
                for (int mi = 0; mi < 4; ++mi)
#pragma unroll
                    for (int ft = 0; ft < 2; ++ft)
                        acc[mi][ft] = __builtin_amdgcn_mfma_f32_16x16x32_bf16(af[mi], bf[ft], acc[mi][ft], 0, 0, 0);
            }
            __syncthreads();
        }
        // fold this m-chunk into colsum: bias + relu + sum over 16 m-rows/lane
#pragma unroll
        for (int mi = 0; mi < 4; ++mi)
#pragma unroll
            for (int ft = 0; ft < 2; ++ft) {
                float s = 0.f;
#pragma unroll
                for (int r = 0; r < 4; ++r)
                    s += fmaxf(acc[mi][ft][r] + bias[ft], 0.f);
                colsum[ft] += s;
            }
    }

    // reduce colsum: quads (shfl) then waves (LDS) -> meanbuf atomics
#pragma unroll
    for (int ft = 0; ft < 2; ++ft) {
        float s = colsum[ft];
        s += __shfl_xor(s, 16);
        s += __shfl_xor(s, 32);
        if (quad == 0) sred[wv][ft * 16 + l15] = s;
    }
    __syncthreads();
    if (tid < 32)
        atomicAdd(&meanbuf[smp * 128 + f0 + tid],
                  (sred[0][tid] + sred[1][tid] + sred[2][tid] + sred[3][tid]) * (1.0f / RR));
    __syncthreads();
    if (tid == 0) {
        __threadfence();               // release before flag
        slast = (atomicAdd(&done[smp], 1) == 3) ? 1 : 0;
    }
    __syncthreads();
    if (slast) {
        __threadfence();               // acquire
        if (tid < HID)
            smv[tid] = __hip_atomic_load(&meanbuf[smp * 128 + tid],
                                         __ATOMIC_RELAXED, __HIP_MEMORY_SCOPE_AGENT);
        __syncthreads();
        if (tid < NOUT) {
            float s = fb[tid];
#pragma unroll
            for (int c = 0; c < HID; ++c) s += smv[c] * fw[c * NOUT + tid];
            out[smp * NOUT + tid] = s;
        }
    }
}

extern "C" void kernel_launch(void* const* d_in, const int* in_sizes, int n_in,
                              void* d_out, int out_size, void* d_ws, size_t ws_size,
                              hipStream_t stream) {
    const float* x   = (const float*)d_in[0];
    const int*   ei  = (const int*)d_in[1];
    const float* c1w = (const float*)d_in[2];
    const float* c1b = (const float*)d_in[3];
    const float* c2w = (const float*)d_in[4];
    const float* c2b = (const float*)d_in[5];
    const float* g1w = (const float*)d_in[6];
    const float* g1b = (const float*)d_in[7];
    const float* g2w = (const float*)d_in[8];
    const float* g2b = (const float*)d_in[9];
    const float* fw  = (const float*)d_in[10];
    const float* fb  = (const float*)d_in[11];
    float* out = (float*)d_out;
    int E  = in_sizes[1] / 2;   // total edges (1048576)
    int es = E / BB;            // edges per sample graph (8192)

    char* ws = (char*)d_ws;
    unsigned short* nodesT = (unsigned short*)(ws);                 // 4 MB  [128][32][512] bf16
    unsigned short* h1     = (unsigned short*)(ws + (4u << 20));    // 16 MB [N][128] bf16
    unsigned short* Ab16   = (unsigned short*)(ws + (37u << 20));   // 512 KB dense A bf16
    float* meanbuf         = (float*)(ws + (37u << 20) + (512u << 10)); // 64 KB [128][128]
    int*   done            = (int*)  (ws + (37u << 20) + (576u << 10)); // 512 B [128]
    unsigned short* w2t    = (unsigned short*)(ws + (37u << 20) + (772u << 10)); // 32 KB

    // prep (block 0) + dense-A build (blocks 1..64) + convs (blocks 65..1088)
    k_convs<<<1089, 512, 0, stream>>>(x, c1w, c1b, c2w, c2b, nodesT,
                                      ei, E, es, Ab16, g2w, w2t, meanbuf, done);

    // GCN layer 1: dense MFMA aggregation + fp32 linear + relu -> h1 bf16
    k_agg1<<<512, 256, 0, stream>>>(Ab16, nodesT, g1w, g1b, h1);

    // GCN layer 2 fused (f-split): lin2 + aggregation + mean + fc
    k_fused2<<<512, 256, 0, stream>>>(h1, w2t, Ab16, g2b,
                                      meanbuf, done, fw, fb, out);
}

// Round 7
// 176.680 us; speedup vs baseline: 1.3287x; 1.3287x over previous
//
#include <hip/hip_runtime.h>
#include <hip/hip_bf16.h>

#define BB   128
#define CIN  9
#define TT   2048
#define RR   512
#define NN   (BB*RR)     // 65536
#define HID  128
#define NOUT 12

typedef __attribute__((ext_vector_type(8))) short short8;
typedef __attribute__((ext_vector_type(4))) float f32x4;

static __device__ inline unsigned short f2bf(float f) {       // RNE f32->bf16
    unsigned int u = __float_as_uint(f);
    unsigned int r = (u + 0x7fffu + ((u >> 16) & 1u)) >> 16;
    return (unsigned short)r;
}
static __device__ inline float bf2f(unsigned short u) {
    return __uint_as_float(((unsigned int)u) << 16);
}

// =======================================================================
// k_convs: [byte-identical to R4 — conv taps via wave-uniform s_load]
//   block 0       : tiny prep — zero meanbuf/done, W2^T bf16 transpose.
//   blocks 1..64  : dense-A build, 8 rows each, LDS-local.
//   blocks 65..1088: fused conv1+relu+pool2 -> conv2+relu+pool2 -> nodesT.
// =======================================================================
__global__ __launch_bounds__(512) void k_convs(const float* __restrict__ x,
        const float* __restrict__ w1, const float* __restrict__ b1,
        const float* __restrict__ w2, const float* __restrict__ b2,
        unsigned short* __restrict__ nodesT,
        const int* __restrict__ ei, int E, int es,
        unsigned short* __restrict__ Ab16,
        const float* __restrict__ g2w, unsigned short* __restrict__ w2t,
        float* __restrict__ meanbuf, int* __restrict__ done) {
    __shared__ __align__(16) union {
        struct { float sx[CIN][268]; float s1[16][132]; } c;   // conv: 18.1 KB
        struct { int cnt[512]; float arow[8][512]; } a;        // A-build: 18.4 KB
    } u;
    int tid = threadIdx.x;
    int bid = blockIdx.x;

    if (bid == 0) {                    // ---- tiny prep ----
        float4 z = make_float4(0.f, 0.f, 0.f, 0.f);
        for (int i = tid; i < 128 * 128 / 4; i += 512) ((float4*)meanbuf)[i] = z;
        if (tid < 128) done[tid] = 0;
        for (int idx = tid; idx < 128 * 128; idx += 512) {
            int c2 = idx >> 7, f = idx & 127;
            w2t[f * 128 + c2] = f2bf(g2w[idx]);
        }
        return;
    }

    if (bid <= 64) {                   // ---- dense-A build: rows [base, base+8) ----
        int base = (bid - 1) * 8;
        u.a.cnt[tid] = 0;
        float4 z = make_float4(0.f, 0.f, 0.f, 0.f);
        float4* az = (float4*)u.a.arow;      // 1024 float4
        az[tid] = z; az[tid + 512] = z;
        __syncthreads();
        for (int i = tid; i < es; i += 512) atomicAdd(&u.a.cnt[ei[E + i]], 1);
        __syncthreads();
        for (int i = tid; i < es; i += 512) {
            int c = ei[E + i];
            if (c >= base && c < base + 8) {
                int r = ei[i];
                float nd = rsqrtf((float)u.a.cnt[r] + 1.0f);
                float dn = rsqrtf((float)u.a.cnt[c] + 1.0f);
                atomicAdd(&u.a.arow[c - base][r], nd * dn);
            }
        }
        if (tid < 8) {                 // self loop
            int r = base + tid;
            float d = rsqrtf((float)u.a.cnt[r] + 1.0f);
            atomicAdd(&u.a.arow[tid][r], d * d);
        }
        __syncthreads();
        {   // convert 8x512 fp32 -> bf16, coalesced row stores
            int row = tid >> 6, c0 = (tid & 63) * 8;
            const float* p = &u.a.arow[row][c0];
            ushort4 o0, o1;
            o0.x = f2bf(p[0]); o0.y = f2bf(p[1]); o0.z = f2bf(p[2]); o0.w = f2bf(p[3]);
            o1.x = f2bf(p[4]); o1.y = f2bf(p[5]); o1.z = f2bf(p[6]); o1.w = f2bf(p[7]);
            *(ushort4*)&Ab16[(size_t)(base + row) * 512 + c0]     = o0;
            *(ushort4*)&Ab16[(size_t)(base + row) * 512 + c0 + 4] = o1;
        }
        return;
    }

    int cb = bid - 65;
    int b  = cb >> 3;
    int r0 = (cb & 7) * 64;
    int wv   = __builtin_amdgcn_readfirstlane(tid >> 6);   // wave 0..7
    int lane = tid & 63;

    for (int idx = tid; idx < CIN * 268; idx += 512) {
        int c = idx / 268, j = idx - c * 268;
        int g = 4 * r0 - 6 + j;
        float v = 0.f;
        if (g >= 0 && g < TT) v = x[(b * CIN + c) * TT + g];
        u.c.sx[c][j] = v;
    }
    __syncthreads();

    // phase B: wave wv covers channels wv*2, wv*2+1 (taps via s_load)
    {
        int c1a = wv * 2, c1b = wv * 2 + 1;
        float biasA = b1[c1a], biasB = b1[c1b];
        for (int pp = lane; pp < 132; pp += 64) {
            int p = 2 * r0 - 2 + pp;
            float valA = 0.f, valB = 0.f;
            if (p >= 0 && p < 1024) {
                float a0A = biasA, a1A = biasA, a0B = biasB, a1B = biasB;
#pragma unroll
                for (int c = 0; c < CIN; ++c) {
                    const float2* px = (const float2*)&u.c.sx[c][2 * pp];
                    float2 q0 = px[0], q1 = px[1], q2 = px[2];
                    {
                        const float* wp = &w1[(c1a * CIN + c) * 5];
                        float k0 = wp[0], k1 = wp[1], k2 = wp[2], k3 = wp[3], k4 = wp[4];
                        a0A += q0.x*k0 + q0.y*k1 + q1.x*k2 + q1.y*k3 + q2.x*k4;
                        a1A += q0.y*k0 + q1.x*k1 + q1.y*k2 + q2.x*k3 + q2.y*k4;
                    }
                    {
                        const float* wp = &w1[(c1b * CIN + c) * 5];
                        float k0 = wp[0], k1 = wp[1], k2 = wp[2], k3 = wp[3], k4 = wp[4];
                        a0B += q0.x*k0 + q0.y*k1 + q1.x*k2 + q1.y*k3 + q2.x*k4;
                        a1B += q0.y*k0 + q1.x*k1 + q1.y*k2 + q2.x*k3 + q2.y*k4;
                    }
                }
                valA = fmaxf(fmaxf(a0A, a1A), 0.f);
                valB = fmaxf(fmaxf(a0B, a1B), 0.f);
            }
            u.c.s1[c1a][pp] = valA;
            u.c.s1[c1b][pp] = valB;
        }
    }
    __syncthreads();

    // phase C: wave wv covers channels wv*4..wv*4+3 -> nodesT bf16
    int rl = lane;
    float acc0[4], acc1[4];
#pragma unroll
    for (int o = 0; o < 4; ++o) {
        float bv = b2[wv * 4 + o];
        acc0[o] = bv; acc1[o] = bv;
    }
#pragma unroll
    for (int c = 0; c < 16; ++c) {
        const float2* ps = (const float2*)&u.c.s1[c][2 * rl];
        float2 q0 = ps[0], q1 = ps[1], q2 = ps[2];
#pragma unroll
        for (int o = 0; o < 4; ++o) {
            const float* wp = &w2[((wv * 4 + o) * 16 + c) * 5];
            float k0 = wp[0], k1 = wp[1], k2 = wp[2], k3 = wp[3], k4 = wp[4];
            acc0[o] += q0.x*k0 + q0.y*k1 + q1.x*k2 + q1.y*k3 + q2.x*k4;
            acc1[o] += q0.y*k0 + q1.x*k1 + q1.y*k2 + q2.x*k3 + q2.y*k4;
        }
    }
    int n = r0 + rl;
    unsigned short* np = nodesT + ((size_t)b * 32 + wv * 4) * 512 + n;
    np[0]    = f2bf(fmaxf(fmaxf(acc0[0], acc1[0]), 0.f));
    np[512]  = f2bf(fmaxf(fmaxf(acc0[1], acc1[1]), 0.f));
    np[1024] = f2bf(fmaxf(fmaxf(acc0[2], acc1[2]), 0.f));
    np[1536] = f2bf(fmaxf(fmaxf(acc0[3], acc1[3]), 0.f));
}

// =======================================================================
// k_agg1: [byte-identical to R4]
// =======================================================================
__global__ __launch_bounds__(256) void k_agg1(const unsigned short* __restrict__ Ab,
        const unsigned short* __restrict__ nT, const float* __restrict__ w1,
        const float* __restrict__ b1, unsigned short* __restrict__ h16) {
    __shared__ unsigned short sA[128][72];
    __shared__ unsigned short sN[32][72];
    __shared__ float sAgg[128][33];
    __shared__ float sw1[32 * 128];
    int tid = threadIdx.x;
    int b  = blockIdx.x >> 2;
    int rb = blockIdx.x & 3;
    int r0 = rb * 128;
    const unsigned short* nb = nT + (size_t)b * 32 * 512;

    {
        const float4* src = (const float4*)w1;
        float4* dst = (float4*)sw1;
#pragma unroll
        for (int i = 0; i < 4; ++i) dst[tid + i * 256] = src[tid + i * 256];
    }

    int wv = tid >> 6, lane = tid & 63;
    int l15 = lane & 15, quad = lane >> 4;
    int mB = wv * 32;
    f32x4 acc[2][2];
#pragma unroll
    for (int i = 0; i < 2; ++i)
#pragma unroll
        for (int j = 0; j < 2; ++j) acc[i][j] = (f32x4){0.f, 0.f, 0.f, 0.f};

    for (int kt = 0; kt < 8; ++kt) {
        int k0 = kt * 64;
        __syncthreads();
#pragma unroll
        for (int i = 0; i < 8; ++i) {
            int idx = tid + i * 256;
            int row = idx >> 4, c4 = (idx & 15) * 4;
            *(ushort4*)&sA[row][c4] = *(const ushort4*)&Ab[(size_t)(r0 + row) * 512 + k0 + c4];
        }
#pragma unroll
        for (int i = 0; i < 2; ++i) {
            int idx = tid + i * 256;
            int f = idx >> 4, c4 = (idx & 15) * 4;
            *(ushort4*)&sN[f][c4] = *(const ushort4*)&nb[(size_t)f * 512 + k0 + c4];
        }
        __syncthreads();
#pragma unroll
        for (int ks = 0; ks < 2; ++ks) {
            int kk = ks * 32 + quad * 8;
            short8 av0 = *(const short8*)&sA[mB + l15][kk];
            short8 av1 = *(const short8*)&sA[mB + 16 + l15][kk];
            short8 bv0 = *(const short8*)&sN[l15][kk];
            short8 bv1 = *(const short8*)&sN[16 + l15][kk];
            acc[0][0] = __builtin_amdgcn_mfma_f32_16x16x32_bf16(av0, bv0, acc[0][0], 0, 0, 0);
            acc[0][1] = __builtin_amdgcn_mfma_f32_16x16x32_bf16(av0, bv1, acc[0][1], 0, 0, 0);
            acc[1][0] = __builtin_amdgcn_mfma_f32_16x16x32_bf16(av1, bv0, acc[1][0], 0, 0, 0);
            acc[1][1] = __builtin_amdgcn_mfma_f32_16x16x32_bf16(av1, bv1, acc[1][1], 0, 0, 0);
        }
    }
    __syncthreads();
#pragma unroll
    for (int mi = 0; mi < 2; ++mi)
#pragma unroll
        for (int ni = 0; ni < 2; ++ni)
#pragma unroll
            for (int r = 0; r < 4; ++r)
                sAgg[mB + mi * 16 + quad * 4 + r][ni * 16 + l15] = acc[mi][ni][r];
    __syncthreads();

    int fq = tid & 31;
    int ng = tid >> 5;
    float4 bv = *(const float4*)&b1[fq * 4];
    for (int ch = 0; ch < 4; ++ch) {
        float a[4][4];
#pragma unroll
        for (int j = 0; j < 4; ++j)
#pragma unroll
            for (int q = 0; q < 4; ++q) a[j][q] = 0.f;
#pragma unroll
        for (int c = 0; c < 32; ++c) {
            float4 wvv = *(const float4*)&sw1[c * 128 + fq * 4];
#pragma unroll
            for (int j = 0; j < 4; ++j) {
                float xc = sAgg[ch * 32 + ng * 4 + j][c];
                a[j][0] += xc * wvv.x; a[j][1] += xc * wvv.y;
                a[j][2] += xc * wvv.z; a[j][3] += xc * wvv.w;
            }
        }
#pragma unroll
        for (int j = 0; j < 4; ++j) {
            ushort4 o;
            o.x = f2bf(fmaxf(a[j][0] + bv.x, 0.f));
            o.y = f2bf(fmaxf(a[j][1] + bv.y, 0.f));
            o.z = f2bf(fmaxf(a[j][2] + bv.z, 0.f));
            o.w = f2bf(fmaxf(a[j][3] + bv.w, 0.f));
            *(ushort4*)&h16[(size_t)(b * 512 + r0 + ch * 32 + ng * 4 + j) * 128 + fq * 4] = o;
        }
    }
}

// =======================================================================
// k_lin2: [byte-identical to R4] MFMA  t = h1 @ W2, output TRANSPOSED
// per sample tT[b][feat][node].
// =======================================================================
__global__ __launch_bounds__(256) void k_lin2(const unsigned short* __restrict__ g16,
        const unsigned short* __restrict__ w2t, unsigned short* __restrict__ tT) {
    __shared__ __align__(16) unsigned short smem2[64 * 136 + 128 * 136];
    unsigned short (*srow)[136] = (unsigned short (*)[136])smem2;
    unsigned short (*swT)[136]  = (unsigned short (*)[136])&smem2[64 * 136];
    unsigned short (*sOut)[72]  = (unsigned short (*)[72])smem2;   // aliases after barrier
    int tid = threadIdx.x;
    int nbase = blockIdx.x * 64;

    {   // stage A rows (64x128 bf16)
        const ushort4* src = (const ushort4*)(g16 + (size_t)nbase * 128);
#pragma unroll
        for (int i = 0; i < 8; ++i) {
            int idx = tid + i * 256;
            int row = idx >> 5, col4 = idx & 31;
            ushort4 v = src[idx];
            *(ushort4*)&srow[row][col4 * 4] = v;
        }
    }
    {   // stage W2^T (128x128 bf16)
        const ushort4* src = (const ushort4*)w2t;
#pragma unroll
        for (int i = 0; i < 16; ++i) {
            int idx = tid + i * 256;
            int f = idx >> 5, c4 = idx & 31;
            ushort4 v = src[idx];
            *(ushort4*)&swT[f][c4 * 4] = v;
        }
    }
    __syncthreads();

    int wv  = tid >> 6;
    int lane = tid & 63;
    int m0 = wv * 16;
    int l15 = lane & 15;
    int quad = lane >> 4;
    f32x4 acc[8];
#pragma unroll
    for (int nt = 0; nt < 8; ++nt) acc[nt] = (f32x4){0.f, 0.f, 0.f, 0.f};
#pragma unroll
    for (int kc = 0; kc < 4; ++kc) {
        int k0 = kc * 32 + quad * 8;
        short8 a = *(const short8*)&srow[m0 + l15][k0];
#pragma unroll
        for (int nt = 0; nt < 8; ++nt) {
            short8 b = *(const short8*)&swT[nt * 16 + l15][k0];
            acc[nt] = __builtin_amdgcn_mfma_f32_16x16x32_bf16(a, b, acc[nt], 0, 0, 0);
        }
    }
    __syncthreads();   // all LDS reads done; safe to alias sOut

#pragma unroll
    for (int nt = 0; nt < 8; ++nt) {
        ushort4 o;
        o.x = f2bf(acc[nt][0]); o.y = f2bf(acc[nt][1]);
        o.z = f2bf(acc[nt][2]); o.w = f2bf(acc[nt][3]);
        *(ushort4*)&sOut[nt * 16 + l15][m0 + quad * 4] = o;   // sOut[feat][row]
    }
    __syncthreads();

    int b = nbase >> 9;
    int rl0 = nbase & 511;
#pragma unroll
    for (int i = 0; i < 8; ++i) {
        int idx = tid + i * 256;
        int col = idx >> 4, r4 = (idx & 15) * 4;
        ushort4 v = *(ushort4*)&sOut[col][r4];
        *(ushort4*)&tT[((size_t)(b * 128 + col)) * 512 + rl0 + r4] = v;
    }
}

// =======================================================================
// k_agg2: R4's kernel with ONE transform — double-buffered LDS +
// issue-early/write-late staging (T14). Loads for step kt+1 are issued
// right after the barrier and land while step kt's 32 MFMAs run; one
// barrier per step (dbuf makes the second redundant). Math, operand
// layout and accumulation order bitwise-identical to R4.
// =======================================================================
__global__ __launch_bounds__(256) void k_agg2(const unsigned short* __restrict__ Ab,
        const unsigned short* __restrict__ tT, const float* __restrict__ b2,
        float* __restrict__ meanbuf, int* __restrict__ done,
        const float* __restrict__ fw, const float* __restrict__ fb,
        float* __restrict__ out) {
    __shared__ unsigned short sA[2][128][72];
    __shared__ unsigned short sB[2][128][72];
    __shared__ float sred[2][128];
    __shared__ float sm[HID];
    __shared__ int slast;
    int tid = threadIdx.x;
    int b  = blockIdx.x >> 2;
    int rb = blockIdx.x & 3;
    int r0 = rb * 128;
    const unsigned short* tb = tT + (size_t)b * 128 * 512;
    int wv = tid >> 6, lane = tid & 63;
    int l15 = lane & 15, quad = lane >> 4;
    int wr = wv >> 1, wc = wv & 1;
    f32x4 acc[4][4];
#pragma unroll
    for (int i = 0; i < 4; ++i)
#pragma unroll
        for (int j = 0; j < 4; ++j) acc[i][j] = (f32x4){0.f, 0.f, 0.f, 0.f};

    // prologue: load kt=0 tile into registers
    ushort4 stA[8], stB[8];
#pragma unroll
    for (int i = 0; i < 8; ++i) {
        int idx = tid + i * 256;
        int row = idx >> 4, c4 = (idx & 15) * 4;
        stA[i] = *(const ushort4*)&Ab[(size_t)(r0 + row) * 512 + c4];
        stB[i] = *(const ushort4*)&tb[(size_t)row * 512 + c4];
    }

    int cur = 0;
    for (int kt = 0; kt < 8; ++kt) {
#pragma unroll
        for (int i = 0; i < 8; ++i) {          // write staged regs -> LDS[cur]
            int idx = tid + i * 256;
            int row = idx >> 4, c4 = (idx & 15) * 4;
            *(ushort4*)&sA[cur][row][c4] = stA[i];
            *(ushort4*)&sB[cur][row][c4] = stB[i];
        }
        __syncthreads();
        if (kt < 7) {                          // issue next-tile loads early
            int k0 = (kt + 1) * 64;
#pragma unroll
            for (int i = 0; i < 8; ++i) {
                int idx = tid + i * 256;
                int row = idx >> 4, c4 = (idx & 15) * 4;
                stA[i] = *(const ushort4*)&Ab[(size_t)(r0 + row) * 512 + k0 + c4];
                stB[i] = *(const ushort4*)&tb[(size_t)row * 512 + k0 + c4];
            }
        }
#pragma unroll
        for (int ks = 0; ks < 2; ++ks) {       // compute current tile
            int kk = ks * 32 + quad * 8;
            short8 av[4], bfr[4];
#pragma unroll
            for (int mi = 0; mi < 4; ++mi)
                av[mi] = *(const short8*)&sA[cur][wr * 64 + mi * 16 + l15][kk];
#pragma unroll
            for (int ni = 0; ni < 4; ++ni)
                bfr[ni] = *(const short8*)&sB[cur][wc * 64 + ni * 16 + l15][kk];
#pragma unroll
            for (int mi = 0; mi < 4; ++mi)
#pragma unroll
                for (int ni = 0; ni < 4; ++ni)
                    acc[mi][ni] = __builtin_amdgcn_mfma_f32_16x16x32_bf16(av[mi], bfr[ni], acc[mi][ni], 0, 0, 0);
        }
        cur ^= 1;
    }

    // epilogue: bias + relu + column sums over this block's 128 rows  [R4]
#pragma unroll
    for (int ni = 0; ni < 4; ++ni) {
        int col = wc * 64 + ni * 16 + l15;
        float bc = b2[col];
        float s = 0.f;
#pragma unroll
        for (int mi = 0; mi < 4; ++mi)
#pragma unroll
            for (int r = 0; r < 4; ++r)
                s += fmaxf(acc[mi][ni][r] + bc, 0.f);
        s += __shfl_xor(s, 16);
        s += __shfl_xor(s, 32);
        if (quad == 0) sred[wr][col] = s;
    }
    __syncthreads();
    if (tid < 128)
        atomicAdd(&meanbuf[b * 128 + tid], (sred[0][tid] + sred[1][tid]) * (1.0f / RR));
    __syncthreads();                       // meanbuf atomics issued block-wide
    if (tid == 0) {
        __threadfence();                   // release before flag
        slast = (atomicAdd(&done[b], 1) == 3) ? 1 : 0;
    }
    __syncthreads();                       // slast uniform across block
    if (slast) {
        __threadfence();                   // acquire
        if (tid < HID)
            sm[tid] = __hip_atomic_load(&meanbuf[b * 128 + tid],
                                        __ATOMIC_RELAXED, __HIP_MEMORY_SCOPE_AGENT);
        __syncthreads();
        if (tid < NOUT) {
            float s = fb[tid];
#pragma unroll
            for (int c = 0; c < HID; ++c) s += sm[c] * fw[c * NOUT + tid];
            out[b * NOUT + tid] = s;
        }
    }
}

extern "C" void kernel_launch(void* const* d_in, const int* in_sizes, int n_in,
                              void* d_out, int out_size, void* d_ws, size_t ws_size,
                              hipStream_t stream) {
    const float* x   = (const float*)d_in[0];
    const int*   ei  = (const int*)d_in[1];
    const float* c1w = (const float*)d_in[2];
    const float* c1b = (const float*)d_in[3];
    const float* c2w = (const float*)d_in[4];
    const float* c2b = (const float*)d_in[5];
    const float* g1w = (const float*)d_in[6];
    const float* g1b = (const float*)d_in[7];
    const float* g2w = (const float*)d_in[8];
    const float* g2b = (const float*)d_in[9];
    const float* fw  = (const float*)d_in[10];
    const float* fb  = (const float*)d_in[11];
    float* out = (float*)d_out;
    int E  = in_sizes[1] / 2;   // total edges (1048576)
    int es = E / BB;            // edges per sample graph (8192)

    char* ws = (char*)d_ws;
    unsigned short* nodesT = (unsigned short*)(ws);                 // 4 MB  [128][32][512] bf16
    unsigned short* h1     = (unsigned short*)(ws + (4u << 20));    // 16 MB [N][128] bf16
    unsigned short* tT     = (unsigned short*)(ws + (20u << 20));   // 16.8 MB [128][128][512] bf16
    unsigned short* Ab16   = (unsigned short*)(ws + (37u << 20));   // 512 KB dense A bf16
    float* meanbuf         = (float*)(ws + (37u << 20) + (512u << 10)); // 64 KB [128][128]
    int*   done            = (int*)  (ws + (37u << 20) + (576u << 10)); // 512 B [128]
    unsigned short* w2t    = (unsigned short*)(ws + (37u << 20) + (772u << 10)); // 32 KB

    // prep (block 0) + dense-A build (blocks 1..64) + convs (blocks 65..1088)
    k_convs<<<1089, 512, 0, stream>>>(x, c1w, c1b, c2w, c2b, nodesT,
                                      ei, E, es, Ab16, g2w, w2t, meanbuf, done);

    // GCN layer 1: dense MFMA aggregation + fp32 linear + relu -> h1 bf16
    k_agg1<<<512, 256, 0, stream>>>(Ab16, nodesT, g1w, g1b, h1);

    // GCN layer 2: MFMA linear (transposed output), then pipelined dense
    // MFMA aggregation fused with bias+relu+column-mean atomics + fc
    k_lin2<<<NN / 64, 256, 0, stream>>>(h1, w2t, tT);
    k_agg2<<<512, 256, 0, stream>>>(Ab16, tT, g2b, meanbuf, done, fw, fb, out);
}

// Round 8
// 175.676 us; speedup vs baseline: 1.3363x; 1.0057x over previous
//
#include <hip/hip_runtime.h>
#include <hip/hip_bf16.h>

#define BB   128
#define CIN  9
#define TT   2048
#define RR   512
#define NN   (BB*RR)     // 65536
#define HID  128
#define NOUT 12

typedef __attribute__((ext_vector_type(8))) short short8;
typedef __attribute__((ext_vector_type(4))) float f32x4;

static __device__ inline unsigned short f2bf(float f) {       // RNE f32->bf16
    unsigned int u = __float_as_uint(f);
    unsigned int r = (u + 0x7fffu + ((u >> 16) & 1u)) >> 16;
    return (unsigned short)r;
}
static __device__ inline float bf2f(unsigned short u) {
    return __uint_as_float(((unsigned int)u) << 16);
}

// =======================================================================
// k_convs: [byte-identical to R4/R7 — conv taps via wave-uniform s_load]
//   block 0       : tiny prep — zero meanbuf/done, W2^T bf16 transpose.
//   blocks 1..64  : dense-A build, 8 rows each, LDS-local.
//   blocks 65..1088: fused conv1+relu+pool2 -> conv2+relu+pool2 -> nodesT.
// =======================================================================
__global__ __launch_bounds__(512) void k_convs(const float* __restrict__ x,
        const float* __restrict__ w1, const float* __restrict__ b1,
        const float* __restrict__ w2, const float* __restrict__ b2,
        unsigned short* __restrict__ nodesT,
        const int* __restrict__ ei, int E, int es,
        unsigned short* __restrict__ Ab16,
        const float* __restrict__ g2w, unsigned short* __restrict__ w2t,
        float* __restrict__ meanbuf, int* __restrict__ done) {
    __shared__ __align__(16) union {
        struct { float sx[CIN][268]; float s1[16][132]; } c;   // conv: 18.1 KB
        struct { int cnt[512]; float arow[8][512]; } a;        // A-build: 18.4 KB
    } u;
    int tid = threadIdx.x;
    int bid = blockIdx.x;

    if (bid == 0) {                    // ---- tiny prep ----
        float4 z = make_float4(0.f, 0.f, 0.f, 0.f);
        for (int i = tid; i < 128 * 128 / 4; i += 512) ((float4*)meanbuf)[i] = z;
        if (tid < 128) done[tid] = 0;
        for (int idx = tid; idx < 128 * 128; idx += 512) {
            int c2 = idx >> 7, f = idx & 127;
            w2t[f * 128 + c2] = f2bf(g2w[idx]);
        }
        return;
    }

    if (bid <= 64) {                   // ---- dense-A build: rows [base, base+8) ----
        int base = (bid - 1) * 8;
        u.a.cnt[tid] = 0;
        float4 z = make_float4(0.f, 0.f, 0.f, 0.f);
        float4* az = (float4*)u.a.arow;      // 1024 float4
        az[tid] = z; az[tid + 512] = z;
        __syncthreads();
        for (int i = tid; i < es; i += 512) atomicAdd(&u.a.cnt[ei[E + i]], 1);
        __syncthreads();
        for (int i = tid; i < es; i += 512) {
            int c = ei[E + i];
            if (c >= base && c < base + 8) {
                int r = ei[i];
                float nd = rsqrtf((float)u.a.cnt[r] + 1.0f);
                float dn = rsqrtf((float)u.a.cnt[c] + 1.0f);
                atomicAdd(&u.a.arow[c - base][r], nd * dn);
            }
        }
        if (tid < 8) {                 // self loop
            int r = base + tid;
            float d = rsqrtf((float)u.a.cnt[r] + 1.0f);
            atomicAdd(&u.a.arow[tid][r], d * d);
        }
        __syncthreads();
        {   // convert 8x512 fp32 -> bf16, coalesced row stores
            int row = tid >> 6, c0 = (tid & 63) * 8;
            const float* p = &u.a.arow[row][c0];
            ushort4 o0, o1;
            o0.x = f2bf(p[0]); o0.y = f2bf(p[1]); o0.z = f2bf(p[2]); o0.w = f2bf(p[3]);
            o1.x = f2bf(p[4]); o1.y = f2bf(p[5]); o1.z = f2bf(p[6]); o1.w = f2bf(p[7]);
            *(ushort4*)&Ab16[(size_t)(base + row) * 512 + c0]     = o0;
            *(ushort4*)&Ab16[(size_t)(base + row) * 512 + c0 + 4] = o1;
        }
        return;
    }

    int cb = bid - 65;
    int b  = cb >> 3;
    int r0 = (cb & 7) * 64;
    int wv   = __builtin_amdgcn_readfirstlane(tid >> 6);   // wave 0..7
    int lane = tid & 63;

    for (int idx = tid; idx < CIN * 268; idx += 512) {
        int c = idx / 268, j = idx - c * 268;
        int g = 4 * r0 - 6 + j;
        float v = 0.f;
        if (g >= 0 && g < TT) v = x[(b * CIN + c) * TT + g];
        u.c.sx[c][j] = v;
    }
    __syncthreads();

    // phase B: wave wv covers channels wv*2, wv*2+1 (taps via s_load)
    {
        int c1a = wv * 2, c1b = wv * 2 + 1;
        float biasA = b1[c1a], biasB = b1[c1b];
        for (int pp = lane; pp < 132; pp += 64) {
            int p = 2 * r0 - 2 + pp;
            float valA = 0.f, valB = 0.f;
            if (p >= 0 && p < 1024) {
                float a0A = biasA, a1A = biasA, a0B = biasB, a1B = biasB;
#pragma unroll
                for (int c = 0; c < CIN; ++c) {
                    const float2* px = (const float2*)&u.c.sx[c][2 * pp];
                    float2 q0 = px[0], q1 = px[1], q2 = px[2];
                    {
                        const float* wp = &w1[(c1a * CIN + c) * 5];
                        float k0 = wp[0], k1 = wp[1], k2 = wp[2], k3 = wp[3], k4 = wp[4];
                        a0A += q0.x*k0 + q0.y*k1 + q1.x*k2 + q1.y*k3 + q2.x*k4;
                        a1A += q0.y*k0 + q1.x*k1 + q1.y*k2 + q2.x*k3 + q2.y*k4;
                    }
                    {
                        const float* wp = &w1[(c1b * CIN + c) * 5];
                        float k0 = wp[0], k1 = wp[1], k2 = wp[2], k3 = wp[3], k4 = wp[4];
                        a0B += q0.x*k0 + q0.y*k1 + q1.x*k2 + q1.y*k3 + q2.x*k4;
                        a1B += q0.y*k0 + q1.x*k1 + q1.y*k2 + q2.x*k3 + q2.y*k4;
                    }
                }
                valA = fmaxf(fmaxf(a0A, a1A), 0.f);
                valB = fmaxf(fmaxf(a0B, a1B), 0.f);
            }
            u.c.s1[c1a][pp] = valA;
            u.c.s1[c1b][pp] = valB;
        }
    }
    __syncthreads();

    // phase C: wave wv covers channels wv*4..wv*4+3 -> nodesT bf16
    int rl = lane;
    float acc0[4], acc1[4];
#pragma unroll
    for (int o = 0; o < 4; ++o) {
        float bv = b2[wv * 4 + o];
        acc0[o] = bv; acc1[o] = bv;
    }
#pragma unroll
    for (int c = 0; c < 16; ++c) {
        const float2* ps = (const float2*)&u.c.s1[c][2 * rl];
        float2 q0 = ps[0], q1 = ps[1], q2 = ps[2];
#pragma unroll
        for (int o = 0; o < 4; ++o) {
            const float* wp = &w2[((wv * 4 + o) * 16 + c) * 5];
            float k0 = wp[0], k1 = wp[1], k2 = wp[2], k3 = wp[3], k4 = wp[4];
            acc0[o] += q0.x*k0 + q0.y*k1 + q1.x*k2 + q1.y*k3 + q2.x*k4;
            acc1[o] += q0.y*k0 + q1.x*k1 + q1.y*k2 + q2.x*k3 + q2.y*k4;
        }
    }
    int n = r0 + rl;
    unsigned short* np = nodesT + ((size_t)b * 32 + wv * 4) * 512 + n;
    np[0]    = f2bf(fmaxf(fmaxf(acc0[0], acc1[0]), 0.f));
    np[512]  = f2bf(fmaxf(fmaxf(acc0[1], acc1[1]), 0.f));
    np[1024] = f2bf(fmaxf(fmaxf(acc0[2], acc1[2]), 0.f));
    np[1536] = f2bf(fmaxf(fmaxf(acc0[3], acc1[3]), 0.f));
}

// =======================================================================
// k_l1l2: fused GCN layer-1 (agg MFMA + fp32 lin1) + layer-2 linear.
//   Grid 512 = 128 samples x 4 row-blocks, 256 threads (4 waves).
//   Phase A: agg = A_panel @ nodes_b  — R7-proven dbuf+issue-early staging.
//   Phase B: lin1 fp32 (bitwise-identical to R4 k_agg1), h1 -> LDS bf16.
//   Phase C: t = h1 @ W2 (k_lin2's math; W2^T frags from L2), transpose
//            staging in LDS, coalesced tT stores. h1 never touches HBM.
//   LDS 79.4 KB (aliased) -> 2 blocks/CU.
// =======================================================================
__global__ __launch_bounds__(256) void k_l1l2(const unsigned short* __restrict__ Ab,
        const unsigned short* __restrict__ nT, const float* __restrict__ w1,
        const float* __restrict__ b1, const unsigned short* __restrict__ w2t,
        unsigned short* __restrict__ tT) {
    // flat LDS, phases alias dead regions:
    //  [0,36864)      sA[2][128][72] ushort   | phase C: h1L[128][136] ushort
    //  [36864,46080)  sN[2][32][72]  ushort   | phase C: sOutH[128][72] ushort
    //  [46080,62976)  sAgg[128][33]  float    |   (sOutH spills into this, dead)
    //  [62976,79360)  sw1[4096]      float
    __shared__ __align__(16) char smem[79360];
    unsigned short* sAp  = (unsigned short*)smem;
    unsigned short* sNp  = (unsigned short*)(smem + 36864);
    float*          sAgg = (float*)(smem + 46080);
    float*          sw1  = (float*)(smem + 62976);
    unsigned short* h1L  = (unsigned short*)smem;            // alias (phase C)
    unsigned short* sOutH= (unsigned short*)(smem + 36864);  // alias (phase C)

    int tid = threadIdx.x;
    int b  = blockIdx.x >> 2;
    int rb = blockIdx.x & 3;
    int r0 = rb * 128;
    const unsigned short* nb = nT + (size_t)b * 32 * 512;

    {   // stage W1 (fp32) once
        const float4* src = (const float4*)w1;
        float4* dst = (float4*)sw1;
#pragma unroll
        for (int i = 0; i < 4; ++i) dst[tid + i * 256] = src[tid + i * 256];
    }

    int wv = tid >> 6, lane = tid & 63;
    int l15 = lane & 15, quad = lane >> 4;
    int mB = wv * 32;
    f32x4 acc[2][2];
#pragma unroll
    for (int i = 0; i < 2; ++i)
#pragma unroll
        for (int j = 0; j < 2; ++j) acc[i][j] = (f32x4){0.f, 0.f, 0.f, 0.f};

    // ---- phase A: aggregation MFMA, dbuf + issue-early (R7 pattern) ----
    ushort4 stA[8], stB[2];
#pragma unroll
    for (int i = 0; i < 8; ++i) {
        int idx = tid + i * 256;
        int row = idx >> 4, c4 = (idx & 15) * 4;
        stA[i] = *(const ushort4*)&Ab[(size_t)(r0 + row) * 512 + c4];
    }
#pragma unroll
    for (int i = 0; i < 2; ++i) {
        int idx = tid + i * 256;
        int f = idx >> 4, c4 = (idx & 15) * 4;
        stB[i] = *(const ushort4*)&nb[(size_t)f * 512 + c4];
    }
    int cur = 0;
    for (int kt = 0; kt < 8; ++kt) {
#pragma unroll
        for (int i = 0; i < 8; ++i) {
            int idx = tid + i * 256;
            int row = idx >> 4, c4 = (idx & 15) * 4;
            *(ushort4*)&sAp[(size_t)cur * 9216 + row * 72 + c4] = stA[i];
        }
#pragma unroll
        for (int i = 0; i < 2; ++i) {
            int idx = tid + i * 256;
            int f = idx >> 4, c4 = (idx & 15) * 4;
            *(ushort4*)&sNp[(size_t)cur * 2304 + f * 72 + c4] = stB[i];
        }
        __syncthreads();
        if (kt < 7) {
            int k0 = (kt + 1) * 64;
#pragma unroll
            for (int i = 0; i < 8; ++i) {
                int idx = tid + i * 256;
                int row = idx >> 4, c4 = (idx & 15) * 4;
                stA[i] = *(const ushort4*)&Ab[(size_t)(r0 + row) * 512 + k0 + c4];
            }
#pragma unroll
            for (int i = 0; i < 2; ++i) {
                int idx = tid + i * 256;
                int f = idx >> 4, c4 = (idx & 15) * 4;
                stB[i] = *(const ushort4*)&nb[(size_t)f * 512 + k0 + c4];
            }
        }
#pragma unroll
        for (int ks = 0; ks < 2; ++ks) {
            int kk = ks * 32 + quad * 8;
            short8 av0 = *(const short8*)&sAp[(size_t)cur * 9216 + (mB + l15) * 72 + kk];
            short8 av1 = *(const short8*)&sAp[(size_t)cur * 9216 + (mB + 16 + l15) * 72 + kk];
            short8 bv0 = *(const short8*)&sNp[(size_t)cur * 2304 + l15 * 72 + kk];
            short8 bv1 = *(const short8*)&sNp[(size_t)cur * 2304 + (16 + l15) * 72 + kk];
            acc[0][0] = __builtin_amdgcn_mfma_f32_16x16x32_bf16(av0, bv0, acc[0][0], 0, 0, 0);
            acc[0][1] = __builtin_amdgcn_mfma_f32_16x16x32_bf16(av0, bv1, acc[0][1], 0, 0, 0);
            acc[1][0] = __builtin_amdgcn_mfma_f32_16x16x32_bf16(av1, bv0, acc[1][0], 0, 0, 0);
            acc[1][1] = __builtin_amdgcn_mfma_f32_16x16x32_bf16(av1, bv1, acc[1][1], 0, 0, 0);
        }
        cur ^= 1;
    }
#pragma unroll
    for (int mi = 0; mi < 2; ++mi)
#pragma unroll
        for (int ni = 0; ni < 2; ++ni)
#pragma unroll
            for (int r = 0; r < 4; ++r)
                sAgg[(mB + mi * 16 + quad * 4 + r) * 33 + ni * 16 + l15] = acc[mi][ni][r];
    __syncthreads();

    // ---- phase B: lin1 fp32 (identical math), h1 -> LDS bf16 ----------
    int fq = tid & 31;
    int ng = tid >> 5;
    float4 bv = *(const float4*)&b1[fq * 4];
    for (int ch = 0; ch < 4; ++ch) {
        float a[4][4];
#pragma unroll
        for (int j = 0; j < 4; ++j)
#pragma unroll
            for (int q = 0; q < 4; ++q) a[j][q] = 0.f;
#pragma unroll
        for (int c = 0; c < 32; ++c) {
            float4 wvv = *(const float4*)&sw1[c * 128 + fq * 4];
#pragma unroll
            for (int j = 0; j < 4; ++j) {
                float xc = sAgg[(ch * 32 + ng * 4 + j) * 33 + c];
                a[j][0] += xc * wvv.x; a[j][1] += xc * wvv.y;
                a[j][2] += xc * wvv.z; a[j][3] += xc * wvv.w;
            }
        }
#pragma unroll
        for (int j = 0; j < 4; ++j) {
            int row = ch * 32 + ng * 4 + j;
            ushort4 o;
            o.x = f2bf(fmaxf(a[j][0] + bv.x, 0.f));
            o.y = f2bf(fmaxf(a[j][1] + bv.y, 0.f));
            o.z = f2bf(fmaxf(a[j][2] + bv.z, 0.f));
            o.w = f2bf(fmaxf(a[j][3] + bv.w, 0.f));
            *(ushort4*)&h1L[row * 136 + fq * 4] = o;   // aliases sA (phase A dead)
        }
    }
    __syncthreads();

    // ---- phase C: t = h1 @ W2, transpose-staged tT stores --------------
    for (int h = 0; h < 2; ++h) {
        int m0 = h * 64 + wv * 16;
        f32x4 acc2[8];
#pragma unroll
        for (int nt = 0; nt < 8; ++nt) acc2[nt] = (f32x4){0.f, 0.f, 0.f, 0.f};
#pragma unroll
        for (int kc = 0; kc < 4; ++kc) {
            int k0 = kc * 32 + quad * 8;
            short8 af = *(const short8*)&h1L[(m0 + l15) * 136 + k0];
#pragma unroll
            for (int nt = 0; nt < 8; ++nt) {
                short8 bfr = *(const short8*)&w2t[(size_t)(nt * 16 + l15) * 128 + k0];
                acc2[nt] = __builtin_amdgcn_mfma_f32_16x16x32_bf16(af, bfr, acc2[nt], 0, 0, 0);
            }
        }
        __syncthreads();               // prev sOutH consumers done (and phase B)
#pragma unroll
        for (int nt = 0; nt < 8; ++nt) {
            ushort4 o;
            o.x = f2bf(acc2[nt][0]); o.y = f2bf(acc2[nt][1]);
            o.z = f2bf(acc2[nt][2]); o.w = f2bf(acc2[nt][3]);
            // sOutH[feat][node-local]: 4 consecutive nodes per lane
            *(ushort4*)&sOutH[(nt * 16 + l15) * 72 + wv * 16 + quad * 4] = o;
        }
        __syncthreads();
#pragma unroll
        for (int i = 0; i < 8; ++i) {
            int idx = tid + i * 256;           // 2048 = 128 f x 16 node-groups
            int f = idx >> 4, n4 = (idx & 15) * 4;
            ushort4 v = *(ushort4*)&sOutH[f * 72 + n4];
            *(ushort4*)&tT[((size_t)(b * 128 + f)) * 512 + r0 + h * 64 + n4] = v;
        }
        __syncthreads();
    }
}

// =======================================================================
// k_agg2: [byte-identical to R7 — dbuf + issue-early, fused mean + fc]
// =======================================================================
__global__ __launch_bounds__(256) void k_agg2(const unsigned short* __restrict__ Ab,
        const unsigned short* __restrict__ tT, const float* __restrict__ b2,
        float* __restrict__ meanbuf, int* __restrict__ done,
        const float* __restrict__ fw, const float* __restrict__ fb,
        float* __restrict__ out) {
    __shared__ unsigned short sA[2][128][72];
    __shared__ unsigned short sB[2][128][72];
    __shared__ float sred[2][128];
    __shared__ float sm[HID];
    __shared__ int slast;
    int tid = threadIdx.x;
    int b  = blockIdx.x >> 2;
    int rb = blockIdx.x & 3;
    int r0 = rb * 128;
    const unsigned short* tb = tT + (size_t)b * 128 * 512;
    int wv = tid >> 6, lane = tid & 63;
    int l15 = lane & 15, quad = lane >> 4;
    int wr = wv >> 1, wc = wv & 1;
    f32x4 acc[4][4];
#pragma unroll
    for (int i = 0; i < 4; ++i)
#pragma unroll
        for (int j = 0; j < 4; ++j) acc[i][j] = (f32x4){0.f, 0.f, 0.f, 0.f};

    ushort4 stA[8], stB[8];
#pragma unroll
    for (int i = 0; i < 8; ++i) {
        int idx = tid + i * 256;
        int row = idx >> 4, c4 = (idx & 15) * 4;
        stA[i] = *(const ushort4*)&Ab[(size_t)(r0 + row) * 512 + c4];
        stB[i] = *(const ushort4*)&tb[(size_t)row * 512 + c4];
    }

    int cur = 0;
    for (int kt = 0; kt < 8; ++kt) {
#pragma unroll
        for (int i = 0; i < 8; ++i) {
            int idx = tid + i * 256;
            int row = idx >> 4, c4 = (idx & 15) * 4;
            *(ushort4*)&sA[cur][row][c4] = stA[i];
            *(ushort4*)&sB[cur][row][c4] = stB[i];
        }
        __syncthreads();
        if (kt < 7) {
            int k0 = (kt + 1) * 64;
#pragma unroll
            for (int i = 0; i < 8; ++i) {
                int idx = tid + i * 256;
                int row = idx >> 4, c4 = (idx & 15) * 4;
                stA[i] = *(const ushort4*)&Ab[(size_t)(r0 + row) * 512 + k0 + c4];
                stB[i] = *(const ushort4*)&tb[(size_t)row * 512 + k0 + c4];
            }
        }
#pragma unroll
        for (int ks = 0; ks < 2; ++ks) {
            int kk = ks * 32 + quad * 8;
            short8 av[4], bfr[4];
#pragma unroll
            for (int mi = 0; mi < 4; ++mi)
                av[mi] = *(const short8*)&sA[cur][wr * 64 + mi * 16 + l15][kk];
#pragma unroll
            for (int ni = 0; ni < 4; ++ni)
                bfr[ni] = *(const short8*)&sB[cur][wc * 64 + ni * 16 + l15][kk];
#pragma unroll
            for (int mi = 0; mi < 4; ++mi)
#pragma unroll
                for (int ni = 0; ni < 4; ++ni)
                    acc[mi][ni] = __builtin_amdgcn_mfma_f32_16x16x32_bf16(av[mi], bfr[ni], acc[mi][ni], 0, 0, 0);
        }
        cur ^= 1;
    }

#pragma unroll
    for (int ni = 0; ni < 4; ++ni) {
        int col = wc * 64 + ni * 16 + l15;
        float bc = b2[col];
        float s = 0.f;
#pragma unroll
        for (int mi = 0; mi < 4; ++mi)
#pragma unroll
            for (int r = 0; r < 4; ++r)
                s += fmaxf(acc[mi][ni][r] + bc, 0.f);
        s += __shfl_xor(s, 16);
        s += __shfl_xor(s, 32);
        if (quad == 0) sred[wr][col] = s;
    }
    __syncthreads();
    if (tid < 128)
        atomicAdd(&meanbuf[b * 128 + tid], (sred[0][tid] + sred[1][tid]) * (1.0f / RR));
    __syncthreads();
    if (tid == 0) {
        __threadfence();
        slast = (atomicAdd(&done[b], 1) == 3) ? 1 : 0;
    }
    __syncthreads();
    if (slast) {
        __threadfence();
        if (tid < HID)
            sm[tid] = __hip_atomic_load(&meanbuf[b * 128 + tid],
                                        __ATOMIC_RELAXED, __HIP_MEMORY_SCOPE_AGENT);
        __syncthreads();
        if (tid < NOUT) {
            float s = fb[tid];
#pragma unroll
            for (int c = 0; c < HID; ++c) s += sm[c] * fw[c * NOUT + tid];
            out[b * NOUT + tid] = s;
        }
    }
}

extern "C" void kernel_launch(void* const* d_in, const int* in_sizes, int n_in,
                              void* d_out, int out_size, void* d_ws, size_t ws_size,
                              hipStream_t stream) {
    const float* x   = (const float*)d_in[0];
    const int*   ei  = (const int*)d_in[1];
    const float* c1w = (const float*)d_in[2];
    const float* c1b = (const float*)d_in[3];
    const float* c2w = (const float*)d_in[4];
    const float* c2b = (const float*)d_in[5];
    const float* g1w = (const float*)d_in[6];
    const float* g1b = (const float*)d_in[7];
    const float* g2w = (const float*)d_in[8];
    const float* g2b = (const float*)d_in[9];
    const float* fw  = (const float*)d_in[10];
    const float* fb  = (const float*)d_in[11];
    float* out = (float*)d_out;
    int E  = in_sizes[1] / 2;   // total edges (1048576)
    int es = E / BB;            // edges per sample graph (8192)

    char* ws = (char*)d_ws;
    unsigned short* nodesT = (unsigned short*)(ws);                 // 4 MB  [128][32][512] bf16
    unsigned short* tT     = (unsigned short*)(ws + (20u << 20));   // 16.8 MB [128][128][512] bf16
    unsigned short* Ab16   = (unsigned short*)(ws + (37u << 20));   // 512 KB dense A bf16
    float* meanbuf         = (float*)(ws + (37u << 20) + (512u << 10)); // 64 KB [128][128]
    int*   done            = (int*)  (ws + (37u << 20) + (576u << 10)); // 512 B [128]
    unsigned short* w2t    = (unsigned short*)(ws + (37u << 20) + (772u << 10)); // 32 KB

    // prep (block 0) + dense-A build (blocks 1..64) + convs (blocks 65..1088)
    k_convs<<<1089, 512, 0, stream>>>(x, c1w, c1b, c2w, c2b, nodesT,
                                      ei, E, es, Ab16, g2w, w2t, meanbuf, done);

    // GCN layer 1 + layer-2 linear fused: h1 stays in LDS, writes tT
    k_l1l2<<<512, 256, 0, stream>>>(Ab16, nodesT, g1w, g1b, w2t, tT);

    // GCN layer 2 aggregation (pipelined) + mean + fc
    k_agg2<<<512, 256, 0, stream>>>(Ab16, tT, g2b, meanbuf, done, fw, fb, out);
}